// Round 13
// baseline (292.478 us; speedup 1.0000x reference)
//
#include <hip/hip_runtime.h>

#define NL 16384          // row length
#define NB 64             // rows = blocks
#define NT 1024           // threads per block (16 waves = 4 waves/SIMD)
#define NC (NL / NT)      // 16 elements per thread
#define NW (NT / 64)      // 16 waves
#define N_ITER 12
#define N_IMFS 6

#pragma clang fp contract(off)   // everything unfused EXCEPT the explicit fmaf

#define HSZ (NL + (NL >> 5))   // +1 float per 32: 2-way-max banking (free)
__device__ __forceinline__ int physi(int i) { return i + (i >> 5); }

#define FMAXV 3.402823466e38f

// Frozen bit-exact semantics (R6 value path, absmax 0.0 across R6/R8-R12).
// Protocol history: R7 +157us, R8 +46, R9 +93, R10 +666, R11 +37 -- all
// alternatives to the plain per-epoch grid decision lost. R12 (pass-A diet)
// was NEUTRAL (232 vs 231 steady) => iteration time is latency-bound.
// R12 also showed a 31ms outlier dispatch: the ticket barrier has pollers
// and RMWs on the SAME cache line (64 pollers invalidated per fetch_add) --
// a per-epoch coherence storm, occasionally catastrophic.
// R23 (this): sense-reversing FLAG barrier, value-identical decisions:
//  - arrivals: fetch_add(cnt) -- nobody polls cnt.
//  - release: LAST arriver alone loads the sums, computes the decision,
//    stores sflag = (ep<<1)|dec (release). acq_rel RMW chain orders all
//    64 partial posts before its loads.
//  - wait: everyone polls sflag -- written once per epoch, stable line;
//    63 blocks stop redundantly re-loading sdsl/flsl.
// Same sums, same arithmetic, one computer instead of 64 => bit-identical.
__global__ __launch_bounds__(NT, 4) void emd_main(
    const float* __restrict__ x, float* __restrict__ out,
    unsigned* cnt, double* sdsl, double* flsl) {
  unsigned* sfl = cnt + 16;   // release flag, own 64B line (ws zeroed by host)

  __shared__ float hbuf[2 * HSZ];   // 135168 B: double-buffered h
  __shared__ int wLU[NW], wLL[NW], wNU[NW], wNL[NW];
  __shared__ float wMx[NW], wMn[NW];
  __shared__ unsigned wCT[NW];
  __shared__ int eLU[NW], eLL[NW], eNU[NW], eNL[NW];
  __shared__ float eMx[NW], eMn[NW];
  __shared__ unsigned sTot;
  __shared__ double tA[NW], tB[NW], tC[NW], tD[NW];
  __shared__ int sFlag;

  const int t = threadIdx.x;
  const int lane = t & 63;
  const int wv = t >> 6;
  const int row = blockIdx.x;
  const int base = t * NC;
  const float* xr = x + (size_t)row * NL;
  float* res = out + (size_t)N_IMFS * NB * NL + (size_t)row * NL;

  int off = 0;   // current h buffer offset (0 or HSZ), block-uniform

  // init: h = x row (LDS, swizzled); res slab of d_out = x
  #pragma unroll
  for (int q = 0; q < NC / 4; q++) {
    int i0 = base + q * 4;
    float4 v = *(const float4*)&xr[i0];
    *(float4*)&hbuf[physi(i0)] = v;
    *(float4*)&res[i0] = v;
  }
  __syncthreads();

  unsigned ep = 0;
  bool done = false;

  for (int k = 0; k < N_IMFS; k++) {
    float* outk = out + (size_t)k * NB * NL + (size_t)row * NL;
    if (done) {  // globally-uniform skip (no barriers)
      #pragma unroll
      for (int q = 0; q < NC / 4; q++)
        *(float4*)&outk[base + q * 4] = make_float4(0.f, 0.f, 0.f, 0.f);
      continue;
    }

    // ---------------- sifting ----------------
    for (int it = 0; it < N_ITER; it++) {
      float* hcur = hbuf + off;
      float* hnx  = hbuf + (off ^ HSZ);

      // pass A: chunked rolling walk -> peak masks ONLY (R22 diet)
      unsigned mU = 0, mL = 0;
      {
        float hm = (base > 0) ? hcur[physi(base - 1)] : 0.0f;
        float4 cur = *(const float4*)&hcur[physi(base)];
        #define PKSTEP(J, HC, HP) { int i = base + (J);                     \
          bool in = (i > 0) && (i + 1 < NL);                                \
          if (in && hm < (HC) && (HC) > (HP)) mU |= 1u << (J);              \
          if (in && hm > (HC) && (HC) < (HP)) mL |= 1u << (J);              \
          hm = (HC); }
        #pragma unroll
        for (int q = 0; q < 4; q++) {
          float4 nxt = cur;
          float n0;
          if (q < 3) { nxt = *(const float4*)&hcur[physi(base + q * 4 + 4)]; n0 = nxt.x; }
          else       { n0 = (base + 16 < NL) ? hcur[physi(base + 16)] : 0.0f; }
          PKSTEP(q * 4 + 0, cur.x, cur.y)
          PKSTEP(q * 4 + 1, cur.y, cur.z)
          PKSTEP(q * 4 + 2, cur.z, cur.w)
          PKSTEP(q * 4 + 3, cur.w, n0)
          cur = nxt;
        }
        #undef PKSTEP
      }
      // mask-derived summaries (identical values to the old in-loop trackers)
      int lmU = mU ? (base + 31 - __clz(mU)) : -1;
      int lmL = mL ? (base + 31 - __clz(mL)) : -1;
      int fpU = mU ? (base + __ffs(mU) - 1) : NL;   // first own peak
      int fpL = mL ? (base + __ffs(mL) - 1) : NL;
      int cU = __popc(mU), cL = __popc(mL);
      unsigned long long bUm = __ballot(mU != 0);
      unsigned long long bLm = __ballot(mL != 0);
      // wave summaries: owning lane stores directly (no scans)
      {
        int s;
        s = bUm ? (63 - __clzll((long long)bUm)) : 0;
        if (lane == s) wLU[wv] = bUm ? lmU : -1;
        s = bLm ? (63 - __clzll((long long)bLm)) : 0;
        if (lane == s) wLL[wv] = bLm ? lmL : -1;
        s = bUm ? (__ffsll(bUm) - 1) : 0;
        if (lane == s) wNU[wv] = bUm ? fpU : NL;
        s = bLm ? (__ffsll(bLm) - 1) : 0;
        if (lane == s) wNL[wv] = bLm ? fpL : NL;
      }
      // block peak-count totals (reduce only; same pairwise order as before)
      unsigned ict = ((unsigned)cU << 16) | (unsigned)cL;
      #pragma unroll
      for (int o = 1; o < 64; o <<= 1) {
        unsigned cc = __shfl_down(ict, o, 64);
        if (lane + o < 64) ict += cc;
      }
      if (lane == 0) wCT[wv] = ict;
      __syncthreads();   // S1
      if (t == 0) {      // 16-entry serial combine -> exclusive wave carries
        int aLU = -1, aLL = -1; unsigned tt = 0;
        for (int w = 0; w < NW; w++) {
          eLU[w] = aLU; aLU = max(aLU, wLU[w]);
          eLL[w] = aLL; aLL = max(aLL, wLL[w]);
          tt += wCT[w];
        }
        int aNU = NL, aNL = NL;
        for (int w = NW - 1; w >= 0; w--) {
          eNU[w] = aNU; aNU = min(aNU, wNU[w]);
          eNL[w] = aNL; aNL = min(aNL, wNL[w]);
        }
        sTot = tt;
      }
      __syncthreads();   // S2
      const unsigned tot = sTot;
      const int totU = (int)(tot >> 16), totL = (int)(tot & 0xffffu);

      // per-thread carries via ballot bit-ops + one dynamic shuffle each
      unsigned long long belowU = bUm & ((1ull << lane) - 1ull);
      unsigned long long belowL = bLm & ((1ull << lane) - 1ull);
      unsigned long long aboveU = (lane == 63) ? 0ull : (bUm & (~0ull << (lane + 1)));
      unsigned long long aboveL = (lane == 63) ? 0ull : (bLm & (~0ull << (lane + 1)));
      int slU = belowU ? (63 - __clzll((long long)belowU)) : 0;
      int slL = belowL ? (63 - __clzll((long long)belowL)) : 0;
      int snU = aboveU ? (__ffsll(aboveU) - 1) : 0;
      int snL = aboveL ? (__ffsll(aboveL) - 1) : 0;
      int gU  = __shfl(lmU, slU, 64);
      int gL  = __shfl(lmL, slL, 64);
      int gNU = __shfl(fpU, snU, 64);
      int gNL = __shfl(fpL, snL, 64);
      const int clU = belowU ? gU  : eLU[wv];
      const int clL = belowL ? gL  : eLL[wv];
      const int cnU = aboveU ? gNU : eNU[wv];
      const int cnL = aboveL ? gNL : eNL[wv];

      // Mx/Mn prefix carries only needed for the <2-peaks fallback (rare);
      // tot is block-uniform so the branch (and its barriers) is uniform.
      float crx = -FMAXV, crn = FMAXV;
      if (totU < 2 || totL < 2) {
        float rmx = -FMAXV, rmn = FMAXV;
        #pragma unroll
        for (int q = 0; q < 4; q++) {
          float4 v = *(const float4*)&hcur[physi(base + q * 4)];
          rmx = fmaxf(rmx, v.x); rmn = fminf(rmn, v.x);
          rmx = fmaxf(rmx, v.y); rmn = fminf(rmn, v.y);
          rmx = fmaxf(rmx, v.z); rmn = fminf(rmn, v.z);
          rmx = fmaxf(rmx, v.w); rmn = fminf(rmn, v.w);
        }
        float iMx = rmx, iMn = rmn;
        #pragma unroll
        for (int o = 1; o < 64; o <<= 1) {
          float fa = __shfl_up(iMx, o, 64);
          float fb = __shfl_up(iMn, o, 64);
          if (lane >= o) { iMx = fmaxf(iMx, fa); iMn = fminf(iMn, fb); }
        }
        if (lane == 63) { wMx[wv] = iMx; wMn[wv] = iMn; }
        __syncthreads();
        if (t == 0) {
          float aMx = -FMAXV, aMn = FMAXV;
          for (int w = 0; w < NW; w++) {
            eMx[w] = aMx; aMx = fmaxf(aMx, wMx[w]);
            eMn[w] = aMn; aMn = fminf(aMn, wMn[w]);
          }
        }
        __syncthreads();
        float pMx = __shfl_up(iMx, 1, 64); if (lane == 0) pMx = -FMAXV;
        float pMn = __shfl_up(iMn, 1, 64); if (lane == 0) pMn = FMAXV;
        crx = fmaxf(eMx[wv], pMx);
        crn = fminf(eMn[wv], pMn);
      }

      // pass C: envelopes + mean (frozen f32 ladder), streaming b128 chunks;
      // h_next = hc - mn written inline to the other buffer (dbuf subtract).
      double pm2 = 0.0, ph2 = 0.0;
      {
        float rx = crx, rn = crn;
        int curLU = clU, curLL = clL;
        float vl = hcur[physi(clU < 0 ? 0 : clU)];   // carry-in gathers
        float wl = hcur[physi(clL < 0 ? 0 : clL)];
        int gB = -0x7fffffff, gD = -0x7fffffff;
        float vr = 0.0f, wr = 0.0f;
        #define ENVSTEP(J, HC, OD) { int i = base + (J); float hc = (HC);   \
          rx = fmaxf(rx, hc); rn = fminf(rn, hc);                           \
          if ((mU >> (J)) & 1u) { curLU = i; vl = hc; }                     \
          if ((mL >> (J)) & 1u) { curLL = i; wl = hc; }                     \
          int lU = curLU, lL = curLL;                                       \
          unsigned highm = 0xFFFFFFFFu << (J); unsigned a;                  \
          a = mU & highm; int nUv = a ? (base + __ffs(a) - 1) : cnU;        \
          a = mL & highm; int nLv = a ? (base + __ffs(a) - 1) : cnL;        \
          if (nUv != gB) { gB = nUv; vr = hcur[physi(nUv >= NL ? NL - 1 : nUv)]; } \
          if (nLv != gD) { gD = nLv; wr = hcur[physi(nLv >= NL ? NL - 1 : nLv)]; } \
          int den = nUv - lU;                                               \
          float fracU = (float)(i - lU) / (float)(den > 0 ? den : 1);       \
          float envU = (den > 0) ? __builtin_fmaf(fracU, vr - vl, vl) : vl; \
          if (lU < 0) envU = vr;                                            \
          if (nUv >= NL) envU = vl;                                         \
          if (totU < 2) envU = rx;                                          \
          int den2 = nLv - lL;                                              \
          float fracL = (float)(i - lL) / (float)(den2 > 0 ? den2 : 1);     \
          float envL = (den2 > 0) ? __builtin_fmaf(fracL, wr - wl, wl) : wl;\
          if (lL < 0) envL = wr;                                            \
          if (nLv >= NL) envL = wl;                                         \
          if (totL < 2) envL = rn;                                          \
          float mn = 0.5f * (envU + envL);                                  \
          (OD) = hc - mn;                                                   \
          pm2 += (double)mn * (double)mn; ph2 += (double)hc * (double)hc; }
        #pragma unroll
        for (int q = 0; q < 4; q++) {
          int i0 = base + q * 4;
          float4 hv4 = *(const float4*)&hcur[physi(i0)];
          float4 o4;
          ENVSTEP(q * 4 + 0, hv4.x, o4.x)
          ENVSTEP(q * 4 + 1, hv4.y, o4.y)
          ENVSTEP(q * 4 + 2, hv4.z, o4.z)
          ENVSTEP(q * 4 + 3, hv4.w, o4.w)
          *(float4*)&hnx[physi(i0)] = o4;
        }
        #undef ENVSTEP
      }
      // fused block reduction of (pm2, ph2): wave shuffle, publish, t0 combines
      #pragma unroll
      for (int o = 1; o < 64; o <<= 1) {
        double a = __shfl_down(pm2, o, 64);
        double b = __shfl_down(ph2, o, 64);
        if (lane + o < 64) { pm2 += a; ph2 += b; }
      }
      if (lane == 0) { tA[wv] = pm2; tB[wv] = ph2; }
      // ---- flag barrier + convergence decision (R23) ----
      ep++;
      __syncthreads();   // orders tA/tB (and hnx writes) before t0 / reuse
      if (t == 0) {
        double sA = 0.0, sB = 0.0;
        for (int w = 0; w < NW; w++) { sA += tA[w]; sB += tB[w]; }
        int s = k * N_ITER + it;
        atomicAdd(&sdsl[s * 2 + 0], sA);
        atomicAdd(&sdsl[s * 2 + 1], sB);
        unsigned old = __hip_atomic_fetch_add(cnt, 1u, __ATOMIC_ACQ_REL, __HIP_MEMORY_SCOPE_AGENT);
        if (old == ep * gridDim.x - 1) {   // last arriver: compute + release
          double m2 = __hip_atomic_load(&sdsl[s * 2 + 0],
                                        __ATOMIC_RELAXED, __HIP_MEMORY_SCOPE_AGENT);
          double h2 = __hip_atomic_load(&sdsl[s * 2 + 1],
                                        __ATOMIC_RELAXED, __HIP_MEMORY_SCOPE_AGENT);
          unsigned dec = (m2 / (h2 + 1e-8) < 0.05) ? 1u : 0u;
          __hip_atomic_store(sfl, (ep << 1) | dec, __ATOMIC_RELEASE, __HIP_MEMORY_SCOPE_AGENT);
        }
        unsigned f;
        while (((f = __hip_atomic_load(sfl, __ATOMIC_ACQUIRE, __HIP_MEMORY_SCOPE_AGENT)) >> 1) < ep)
          __builtin_amdgcn_s_sleep(1);
        sFlag = (int)(f & 1u);
      }
      __syncthreads();
      if (sFlag) break;   // converged: keep OLD buffer (h frozen, JAX latch)
      off ^= HSZ;         // accept h_next: uniform flip, no barrier needed
    }

    // ------------- flatness test + outputs (f32 values, f64 sums) -------------
    float* hcur = hbuf + off;
    double s1 = 0.0, s2 = 0.0, s3 = 0.0, s4 = 0.0;
    {
      float rb = 0.0f;   // res-h at base+NC (next thread's first element)
      if (base + NC < NL) rb = res[base + NC] - hcur[physi(base + NC)];
      float4 rv4 = *(const float4*)&res[base];
      float4 hv4 = *(const float4*)&hcur[physi(base)];
      float e0 = rv4.x - hv4.x, e1 = rv4.y - hv4.y,
            e2 = rv4.z - hv4.z, e3 = rv4.w - hv4.w;
      #define FLSTEP(J, CUR, NXT) { int i = base + (J);                     \
        s1 += (double)(CUR); s2 += (double)(CUR) * (double)(CUR);           \
        if (i + 1 < NL) { float dd = (NXT) - (CUR);                         \
          s3 += (double)dd; s4 += (double)dd * (double)dd; } }
      #pragma unroll
      for (int q = 0; q < 4; q++) {
        float c0 = e0, c1 = e1, c2 = e2, c3 = e3;
        float n0;
        if (q < 3) {
          int i0 = base + q * 4 + 4;
          rv4 = *(const float4*)&res[i0];
          hv4 = *(const float4*)&hcur[physi(i0)];
          e0 = rv4.x - hv4.x; e1 = rv4.y - hv4.y;
          e2 = rv4.z - hv4.z; e3 = rv4.w - hv4.w;
          n0 = e0;
        } else n0 = rb;
        FLSTEP(q * 4 + 0, c0, c1)
        FLSTEP(q * 4 + 1, c1, c2)
        FLSTEP(q * 4 + 2, c2, c3)
        FLSTEP(q * 4 + 3, c3, n0)
      }
      #undef FLSTEP
    }
    #pragma unroll
    for (int o = 1; o < 64; o <<= 1) {
      double a = __shfl_down(s1, o, 64);
      double b = __shfl_down(s2, o, 64);
      double c = __shfl_down(s3, o, 64);
      double d = __shfl_down(s4, o, 64);
      if (lane + o < 64) { s1 += a; s2 += b; s3 += c; s4 += d; }
    }
    if (lane == 0) { tA[wv] = s1; tB[wv] = s2; tC[wv] = s3; tD[wv] = s4; }
    __syncthreads();   // orders publishes AND all cross-thread h/res reads above
    if (t == 0) {
      double S1 = 0.0, S2 = 0.0, S3 = 0.0, S4 = 0.0;
      for (int w = 0; w < NW; w++) { S1 += tA[w]; S2 += tB[w]; S3 += tC[w]; S4 += tD[w]; }
      atomicAdd(&flsl[k * 4 + 0], S1);
      atomicAdd(&flsl[k * 4 + 1], S2);
      atomicAdd(&flsl[k * 4 + 2], S3);
      atomicAdd(&flsl[k * 4 + 3], S4);
    }
    // outputs: IMF k = h; res -= h; h <- new res (current buffer)
    #pragma unroll
    for (int q = 0; q < NC / 4; q++) {
      int i0 = base + q * 4;
      int p0 = physi(i0);
      float4 rv = *(const float4*)&res[i0];
      float4 hv = *(const float4*)&hcur[p0];
      float4 rq = make_float4(rv.x - hv.x, rv.y - hv.y, rv.z - hv.z, rv.w - hv.w);
      *(float4*)&outk[i0] = hv;
      *(float4*)&res[i0] = rq;
      *(float4*)&hcur[p0] = rq;
    }
    // ---- flag barrier + flatness decision (R23) ----
    ep++;
    __syncthreads();
    if (t == 0) {
      unsigned old = __hip_atomic_fetch_add(cnt, 1u, __ATOMIC_ACQ_REL, __HIP_MEMORY_SCOPE_AGENT);
      if (old == ep * gridDim.x - 1) {   // last arriver: compute + release
        double S1 = __hip_atomic_load(&flsl[k * 4 + 0], __ATOMIC_RELAXED, __HIP_MEMORY_SCOPE_AGENT);
        double S2 = __hip_atomic_load(&flsl[k * 4 + 1], __ATOMIC_RELAXED, __HIP_MEMORY_SCOPE_AGENT);
        double S3 = __hip_atomic_load(&flsl[k * 4 + 2], __ATOMIC_RELAXED, __HIP_MEMORY_SCOPE_AGENT);
        double S4 = __hip_atomic_load(&flsl[k * 4 + 3], __ATOMIC_RELAXED, __HIP_MEMORY_SCOPE_AGENT);
        double nr = (double)NB * (double)NL;
        double nd = (double)NB * (double)(NL - 1);
        double varr = (S2 - S1 * S1 / nr) / (nr - 1.0);
        double vard = (S4 - S3 * S3 / nd) / (nd - 1.0);
        unsigned dec = (vard < 0.05 * varr) ? 1u : 0u;
        __hip_atomic_store(sfl, (ep << 1) | dec, __ATOMIC_RELEASE, __HIP_MEMORY_SCOPE_AGENT);
      }
      unsigned f;
      while (((f = __hip_atomic_load(sfl, __ATOMIC_ACQUIRE, __HIP_MEMORY_SCOPE_AGENT)) >> 1) < ep)
        __builtin_amdgcn_s_sleep(1);
      sFlag = (int)(f & 1u);
    }
    __syncthreads();
    done = done || (sFlag != 0);
  }
}

extern "C" void kernel_launch(void* const* d_in, const int* in_sizes, int n_in,
                              void* d_out, int out_size, void* d_ws, size_t ws_size,
                              hipStream_t stream) {
  const float* x = (const float*)d_in[0];
  float* out = (float*)d_out;
  // ws layout: [0] arrive counter; [64] release flag; [256] sd slots
  // (6*12*2 dbl); [1408] flat slots (6*4 dbl)
  size_t zb = ws_size < 4096 ? ws_size : 4096;
  hipMemsetAsync(d_ws, 0, zb, stream);
  unsigned* cnt = (unsigned*)d_ws;
  double* sdsl = (double*)((char*)d_ws + 256);
  double* flsl = (double*)((char*)d_ws + 256 + (size_t)N_IMFS * N_ITER * 2 * 8);
  hipLaunchKernelGGL(emd_main, dim3(NB), dim3(NT), 0, stream, x, out, cnt, sdsl, flsl);
}

// Round 14
// 285.811 us; speedup vs baseline: 1.0233x; 1.0233x over previous
//
#include <hip/hip_runtime.h>

#define NL 16384          // row length
#define NB 64             // rows = blocks
#define NT 1024           // threads per block (16 waves = 4 waves/SIMD)
#define NC (NL / NT)      // 16 elements per thread
#define NW (NT / 64)      // 16 waves
#define N_ITER 12
#define N_IMFS 6

#pragma clang fp contract(off)   // everything unfused EXCEPT the explicit fmaf

#define HSZ (NL + (NL >> 5))   // +1 float per 32: 2-way-max banking (free)
__device__ __forceinline__ int physi(int i) { return i + (i >> 5); }

#define FMAXV 3.402823466e38f

// Frozen bit-exact semantics (R6 value path, absmax 0.0 across R6/R8-R13).
// Protocol verdicts: R7 +157, R8 +46, R9 +93, R10 +666, R11 +37, R13 +8 --
// R6's ticket barrier with DISTRIBUTED decision (all blocks poll cnt, then
// all read sums concurrently) beats every alternative. R12 inst-diet:
// neutral (latency-bound). Epoch census (R10 bank-conflict ratio): conv at
// j*~=1, flat never fires -> 18 epochs (2 sift + 1 flat per IMF).
// R24 (this): merge the flat epoch into the NEXT IMF's first sift epoch --
// zero new mechanics. Flat partials posted fire-and-forget at IMF k's
// output phase; done_k resolved at IMF k+1's it=0 ticket wait (the acq_rel
// chain already orders the posts). IMF k+1's it=0 sift runs speculatively;
// if flat fired (never on this data) it is discarded: outputs zeros, res
// already correct -- the exact R9-R11-certified full-IMF-lag mechanism.
// 18 -> 12 epochs. Barrier code + decision arithmetic byte-identical.
__global__ __launch_bounds__(NT, 4) void emd_main(
    const float* __restrict__ x, float* __restrict__ out,
    unsigned* cnt, double* sdsl, double* flsl) {
  __shared__ float hbuf[2 * HSZ];   // 135168 B: double-buffered h
  __shared__ int wLU[NW], wLL[NW], wNU[NW], wNL[NW];
  __shared__ float wMx[NW], wMn[NW];
  __shared__ unsigned wCT[NW];
  __shared__ int eLU[NW], eLL[NW], eNU[NW], eNL[NW];
  __shared__ float eMx[NW], eMn[NW];
  __shared__ unsigned sTot;
  __shared__ double tA[NW], tB[NW], tC[NW], tD[NW];
  __shared__ int sFlag;

  const int t = threadIdx.x;
  const int lane = t & 63;
  const int wv = t >> 6;
  const int row = blockIdx.x;
  const int base = t * NC;
  const float* xr = x + (size_t)row * NL;
  float* res = out + (size_t)N_IMFS * NB * NL + (size_t)row * NL;

  int off = 0;   // current h buffer offset (0 or HSZ), block-uniform

  // init: h = x row (LDS, swizzled); res slab of d_out = x
  #pragma unroll
  for (int q = 0; q < NC / 4; q++) {
    int i0 = base + q * 4;
    float4 v = *(const float4*)&xr[i0];
    *(float4*)&hbuf[physi(i0)] = v;
    *(float4*)&res[i0] = v;
  }
  __syncthreads();

  unsigned ep = 0;
  bool done = false;

  for (int k = 0; k < N_IMFS; k++) {
    float* outk = out + (size_t)k * NB * NL + (size_t)row * NL;
    if (done) {  // globally-uniform skip (no barriers)
      #pragma unroll
      for (int q = 0; q < NC / 4; q++)
        *(float4*)&outk[base + q * 4] = make_float4(0.f, 0.f, 0.f, 0.f);
      continue;
    }

    // ---------------- sifting ----------------
    bool discard = false;
    for (int it = 0; it < N_ITER; it++) {
      float* hcur = hbuf + off;
      float* hnx  = hbuf + (off ^ HSZ);

      // pass A: chunked rolling walk -> peak masks ONLY (R22 diet)
      unsigned mU = 0, mL = 0;
      {
        float hm = (base > 0) ? hcur[physi(base - 1)] : 0.0f;
        float4 cur = *(const float4*)&hcur[physi(base)];
        #define PKSTEP(J, HC, HP) { int i = base + (J);                     \
          bool in = (i > 0) && (i + 1 < NL);                                \
          if (in && hm < (HC) && (HC) > (HP)) mU |= 1u << (J);              \
          if (in && hm > (HC) && (HC) < (HP)) mL |= 1u << (J);              \
          hm = (HC); }
        #pragma unroll
        for (int q = 0; q < 4; q++) {
          float4 nxt = cur;
          float n0;
          if (q < 3) { nxt = *(const float4*)&hcur[physi(base + q * 4 + 4)]; n0 = nxt.x; }
          else       { n0 = (base + 16 < NL) ? hcur[physi(base + 16)] : 0.0f; }
          PKSTEP(q * 4 + 0, cur.x, cur.y)
          PKSTEP(q * 4 + 1, cur.y, cur.z)
          PKSTEP(q * 4 + 2, cur.z, cur.w)
          PKSTEP(q * 4 + 3, cur.w, n0)
          cur = nxt;
        }
        #undef PKSTEP
      }
      // mask-derived summaries (identical values to the old in-loop trackers)
      int lmU = mU ? (base + 31 - __clz(mU)) : -1;
      int lmL = mL ? (base + 31 - __clz(mL)) : -1;
      int fpU = mU ? (base + __ffs(mU) - 1) : NL;   // first own peak
      int fpL = mL ? (base + __ffs(mL) - 1) : NL;
      int cU = __popc(mU), cL = __popc(mL);
      unsigned long long bUm = __ballot(mU != 0);
      unsigned long long bLm = __ballot(mL != 0);
      // wave summaries: owning lane stores directly (no scans)
      {
        int s;
        s = bUm ? (63 - __clzll((long long)bUm)) : 0;
        if (lane == s) wLU[wv] = bUm ? lmU : -1;
        s = bLm ? (63 - __clzll((long long)bLm)) : 0;
        if (lane == s) wLL[wv] = bLm ? lmL : -1;
        s = bUm ? (__ffsll(bUm) - 1) : 0;
        if (lane == s) wNU[wv] = bUm ? fpU : NL;
        s = bLm ? (__ffsll(bLm) - 1) : 0;
        if (lane == s) wNL[wv] = bLm ? fpL : NL;
      }
      // block peak-count totals (reduce only; same pairwise order as before)
      unsigned ict = ((unsigned)cU << 16) | (unsigned)cL;
      #pragma unroll
      for (int o = 1; o < 64; o <<= 1) {
        unsigned cc = __shfl_down(ict, o, 64);
        if (lane + o < 64) ict += cc;
      }
      if (lane == 0) wCT[wv] = ict;
      __syncthreads();   // S1
      if (t == 0) {      // 16-entry serial combine -> exclusive wave carries
        int aLU = -1, aLL = -1; unsigned tt = 0;
        for (int w = 0; w < NW; w++) {
          eLU[w] = aLU; aLU = max(aLU, wLU[w]);
          eLL[w] = aLL; aLL = max(aLL, wLL[w]);
          tt += wCT[w];
        }
        int aNU = NL, aNL = NL;
        for (int w = NW - 1; w >= 0; w--) {
          eNU[w] = aNU; aNU = min(aNU, wNU[w]);
          eNL[w] = aNL; aNL = min(aNL, wNL[w]);
        }
        sTot = tt;
      }
      __syncthreads();   // S2
      const unsigned tot = sTot;
      const int totU = (int)(tot >> 16), totL = (int)(tot & 0xffffu);

      // per-thread carries via ballot bit-ops + one dynamic shuffle each
      unsigned long long belowU = bUm & ((1ull << lane) - 1ull);
      unsigned long long belowL = bLm & ((1ull << lane) - 1ull);
      unsigned long long aboveU = (lane == 63) ? 0ull : (bUm & (~0ull << (lane + 1)));
      unsigned long long aboveL = (lane == 63) ? 0ull : (bLm & (~0ull << (lane + 1)));
      int slU = belowU ? (63 - __clzll((long long)belowU)) : 0;
      int slL = belowL ? (63 - __clzll((long long)belowL)) : 0;
      int snU = aboveU ? (__ffsll(aboveU) - 1) : 0;
      int snL = aboveL ? (__ffsll(aboveL) - 1) : 0;
      int gU  = __shfl(lmU, slU, 64);
      int gL  = __shfl(lmL, slL, 64);
      int gNU = __shfl(fpU, snU, 64);
      int gNL = __shfl(fpL, snL, 64);
      const int clU = belowU ? gU  : eLU[wv];
      const int clL = belowL ? gL  : eLL[wv];
      const int cnU = aboveU ? gNU : eNU[wv];
      const int cnL = aboveL ? gNL : eNL[wv];

      // Mx/Mn prefix carries only needed for the <2-peaks fallback (rare);
      // tot is block-uniform so the branch (and its barriers) is uniform.
      float crx = -FMAXV, crn = FMAXV;
      if (totU < 2 || totL < 2) {
        float rmx = -FMAXV, rmn = FMAXV;
        #pragma unroll
        for (int q = 0; q < 4; q++) {
          float4 v = *(const float4*)&hcur[physi(base + q * 4)];
          rmx = fmaxf(rmx, v.x); rmn = fminf(rmn, v.x);
          rmx = fmaxf(rmx, v.y); rmn = fminf(rmn, v.y);
          rmx = fmaxf(rmx, v.z); rmn = fminf(rmn, v.z);
          rmx = fmaxf(rmx, v.w); rmn = fminf(rmn, v.w);
        }
        float iMx = rmx, iMn = rmn;
        #pragma unroll
        for (int o = 1; o < 64; o <<= 1) {
          float fa = __shfl_up(iMx, o, 64);
          float fb = __shfl_up(iMn, o, 64);
          if (lane >= o) { iMx = fmaxf(iMx, fa); iMn = fminf(iMn, fb); }
        }
        if (lane == 63) { wMx[wv] = iMx; wMn[wv] = iMn; }
        __syncthreads();
        if (t == 0) {
          float aMx = -FMAXV, aMn = FMAXV;
          for (int w = 0; w < NW; w++) {
            eMx[w] = aMx; aMx = fmaxf(aMx, wMx[w]);
            eMn[w] = aMn; aMn = fminf(aMn, wMn[w]);
          }
        }
        __syncthreads();
        float pMx = __shfl_up(iMx, 1, 64); if (lane == 0) pMx = -FMAXV;
        float pMn = __shfl_up(iMn, 1, 64); if (lane == 0) pMn = FMAXV;
        crx = fmaxf(eMx[wv], pMx);
        crn = fminf(eMn[wv], pMn);
      }

      // pass C: envelopes + mean (frozen f32 ladder), streaming b128 chunks;
      // h_next = hc - mn written inline to the other buffer (dbuf subtract).
      double pm2 = 0.0, ph2 = 0.0;
      {
        float rx = crx, rn = crn;
        int curLU = clU, curLL = clL;
        float vl = hcur[physi(clU < 0 ? 0 : clU)];   // carry-in gathers
        float wl = hcur[physi(clL < 0 ? 0 : clL)];
        int gB = -0x7fffffff, gD = -0x7fffffff;
        float vr = 0.0f, wr = 0.0f;
        #define ENVSTEP(J, HC, OD) { int i = base + (J); float hc = (HC);   \
          rx = fmaxf(rx, hc); rn = fminf(rn, hc);                           \
          if ((mU >> (J)) & 1u) { curLU = i; vl = hc; }                     \
          if ((mL >> (J)) & 1u) { curLL = i; wl = hc; }                     \
          int lU = curLU, lL = curLL;                                       \
          unsigned highm = 0xFFFFFFFFu << (J); unsigned a;                  \
          a = mU & highm; int nUv = a ? (base + __ffs(a) - 1) : cnU;        \
          a = mL & highm; int nLv = a ? (base + __ffs(a) - 1) : cnL;        \
          if (nUv != gB) { gB = nUv; vr = hcur[physi(nUv >= NL ? NL - 1 : nUv)]; } \
          if (nLv != gD) { gD = nLv; wr = hcur[physi(nLv >= NL ? NL - 1 : nLv)]; } \
          int den = nUv - lU;                                               \
          float fracU = (float)(i - lU) / (float)(den > 0 ? den : 1);       \
          float envU = (den > 0) ? __builtin_fmaf(fracU, vr - vl, vl) : vl; \
          if (lU < 0) envU = vr;                                            \
          if (nUv >= NL) envU = vl;                                         \
          if (totU < 2) envU = rx;                                          \
          int den2 = nLv - lL;                                              \
          float fracL = (float)(i - lL) / (float)(den2 > 0 ? den2 : 1);     \
          float envL = (den2 > 0) ? __builtin_fmaf(fracL, wr - wl, wl) : wl;\
          if (lL < 0) envL = wr;                                            \
          if (nLv >= NL) envL = wl;                                         \
          if (totL < 2) envL = rn;                                          \
          float mn = 0.5f * (envU + envL);                                  \
          (OD) = hc - mn;                                                   \
          pm2 += (double)mn * (double)mn; ph2 += (double)hc * (double)hc; }
        #pragma unroll
        for (int q = 0; q < 4; q++) {
          int i0 = base + q * 4;
          float4 hv4 = *(const float4*)&hcur[physi(i0)];
          float4 o4;
          ENVSTEP(q * 4 + 0, hv4.x, o4.x)
          ENVSTEP(q * 4 + 1, hv4.y, o4.y)
          ENVSTEP(q * 4 + 2, hv4.z, o4.z)
          ENVSTEP(q * 4 + 3, hv4.w, o4.w)
          *(float4*)&hnx[physi(i0)] = o4;
        }
        #undef ENVSTEP
      }
      // fused block reduction of (pm2, ph2): wave shuffle, publish, t0 combines
      #pragma unroll
      for (int o = 1; o < 64; o <<= 1) {
        double a = __shfl_down(pm2, o, 64);
        double b = __shfl_down(ph2, o, 64);
        if (lane + o < 64) { pm2 += a; ph2 += b; }
      }
      if (lane == 0) { tA[wv] = pm2; tB[wv] = ph2; }
      // ---- grid barrier + convergence (+ lagged flat at it==0) ----
      ep++;
      __syncthreads();   // orders tA/tB (and hnx writes) before t0 / reuse
      if (t == 0) {
        double sA = 0.0, sB = 0.0;
        for (int w = 0; w < NW; w++) { sA += tA[w]; sB += tB[w]; }
        int s = k * N_ITER + it;
        atomicAdd(&sdsl[s * 2 + 0], sA);
        atomicAdd(&sdsl[s * 2 + 1], sB);
        __hip_atomic_fetch_add(cnt, 1u, __ATOMIC_ACQ_REL, __HIP_MEMORY_SCOPE_AGENT);
        unsigned tgt = ep * gridDim.x;
        while (__hip_atomic_load(cnt, __ATOMIC_ACQUIRE, __HIP_MEMORY_SCOPE_AGENT) < tgt)
          __builtin_amdgcn_s_sleep(1);
        int fl = 0;
        if (it == 0 && k > 0) {   // resolve flat_{k-1} (posted last IMF,
          // ordered by this epoch's acq_rel ticket chain)
          double S1 = __hip_atomic_load(&flsl[(k - 1) * 4 + 0], __ATOMIC_RELAXED, __HIP_MEMORY_SCOPE_AGENT);
          double S2 = __hip_atomic_load(&flsl[(k - 1) * 4 + 1], __ATOMIC_RELAXED, __HIP_MEMORY_SCOPE_AGENT);
          double S3 = __hip_atomic_load(&flsl[(k - 1) * 4 + 2], __ATOMIC_RELAXED, __HIP_MEMORY_SCOPE_AGENT);
          double S4 = __hip_atomic_load(&flsl[(k - 1) * 4 + 3], __ATOMIC_RELAXED, __HIP_MEMORY_SCOPE_AGENT);
          double nr = (double)NB * (double)NL;
          double nd = (double)NB * (double)(NL - 1);
          double varr = (S2 - S1 * S1 / nr) / (nr - 1.0);
          double vard = (S4 - S3 * S3 / nd) / (nd - 1.0);
          fl = (vard < 0.05 * varr) ? 1 : 0;
        }
        double m2 = __hip_atomic_load(&sdsl[s * 2 + 0],
                                      __ATOMIC_RELAXED, __HIP_MEMORY_SCOPE_AGENT);
        double h2 = __hip_atomic_load(&sdsl[s * 2 + 1],
                                      __ATOMIC_RELAXED, __HIP_MEMORY_SCOPE_AGENT);
        int cv = (m2 / (h2 + 1e-8) < 0.05) ? 1 : 0;
        sFlag = (fl << 1) | cv;
      }
      __syncthreads();
      if (sFlag & 2) { discard = true; break; }  // flat at k-1: IMF k void
      if (sFlag & 1) break;   // converged: keep OLD buffer (h frozen)
      off ^= HSZ;             // accept h_next: uniform flip
    }
    if (discard) {   // ref: IMFs k.. are zeros, res unchanged (already true)
      done = true;
      #pragma unroll
      for (int q = 0; q < NC / 4; q++)
        *(float4*)&outk[base + q * 4] = make_float4(0.f, 0.f, 0.f, 0.f);
      continue;
    }

    // ------------- flatness test + outputs (f32 values, f64 sums) -------------
    float* hcur = hbuf + off;
    double s1 = 0.0, s2 = 0.0, s3 = 0.0, s4 = 0.0;
    {
      float rb = 0.0f;   // res-h at base+NC (next thread's first element)
      if (base + NC < NL) rb = res[base + NC] - hcur[physi(base + NC)];
      float4 rv4 = *(const float4*)&res[base];
      float4 hv4 = *(const float4*)&hcur[physi(base)];
      float e0 = rv4.x - hv4.x, e1 = rv4.y - hv4.y,
            e2 = rv4.z - hv4.z, e3 = rv4.w - hv4.w;
      #define FLSTEP(J, CUR, NXT) { int i = base + (J);                     \
        s1 += (double)(CUR); s2 += (double)(CUR) * (double)(CUR);           \
        if (i + 1 < NL) { float dd = (NXT) - (CUR);                         \
          s3 += (double)dd; s4 += (double)dd * (double)dd; } }
      #pragma unroll
      for (int q = 0; q < 4; q++) {
        float c0 = e0, c1 = e1, c2 = e2, c3 = e3;
        float n0;
        if (q < 3) {
          int i0 = base + q * 4 + 4;
          rv4 = *(const float4*)&res[i0];
          hv4 = *(const float4*)&hcur[physi(i0)];
          e0 = rv4.x - hv4.x; e1 = rv4.y - hv4.y;
          e2 = rv4.z - hv4.z; e3 = rv4.w - hv4.w;
          n0 = e0;
        } else n0 = rb;
        FLSTEP(q * 4 + 0, c0, c1)
        FLSTEP(q * 4 + 1, c1, c2)
        FLSTEP(q * 4 + 2, c2, c3)
        FLSTEP(q * 4 + 3, c3, n0)
      }
      #undef FLSTEP
    }
    #pragma unroll
    for (int o = 1; o < 64; o <<= 1) {
      double a = __shfl_down(s1, o, 64);
      double b = __shfl_down(s2, o, 64);
      double c = __shfl_down(s3, o, 64);
      double d = __shfl_down(s4, o, 64);
      if (lane + o < 64) { s1 += a; s2 += b; s3 += c; s4 += d; }
    }
    if (lane == 0) { tA[wv] = s1; tB[wv] = s2; tC[wv] = s3; tD[wv] = s4; }
    __syncthreads();   // orders publishes AND all cross-thread h/res reads above
    if (t == 0) {      // post flat partials FIRE-AND-FORGET (R24: no epoch;
      // resolved at IMF k+1's it=0 ticket wait)
      double S1 = 0.0, S2 = 0.0, S3 = 0.0, S4 = 0.0;
      for (int w = 0; w < NW; w++) { S1 += tA[w]; S2 += tB[w]; S3 += tC[w]; S4 += tD[w]; }
      atomicAdd(&flsl[k * 4 + 0], S1);
      atomicAdd(&flsl[k * 4 + 1], S2);
      atomicAdd(&flsl[k * 4 + 2], S3);
      atomicAdd(&flsl[k * 4 + 3], S4);
    }
    // outputs: IMF k = h; res -= h; h <- new res (current buffer)
    #pragma unroll
    for (int q = 0; q < NC / 4; q++) {
      int i0 = base + q * 4;
      int p0 = physi(i0);
      float4 rv = *(const float4*)&res[i0];
      float4 hv = *(const float4*)&hcur[p0];
      float4 rq = make_float4(rv.x - hv.x, rv.y - hv.y, rv.z - hv.z, rv.w - hv.w);
      *(float4*)&outk[i0] = hv;
      *(float4*)&res[i0] = rq;
      *(float4*)&hcur[p0] = rq;
    }
    __syncthreads();   // orders h <- res writes before next IMF's pass A
  }
}

extern "C" void kernel_launch(void* const* d_in, const int* in_sizes, int n_in,
                              void* d_out, int out_size, void* d_ws, size_t ws_size,
                              hipStream_t stream) {
  const float* x = (const float*)d_in[0];
  float* out = (float*)d_out;
  // ws layout: [0] barrier counter; [256] sd slots (6*12*2 dbl); [1408] flat slots (6*4 dbl)
  size_t zb = ws_size < 4096 ? ws_size : 4096;
  hipMemsetAsync(d_ws, 0, zb, stream);
  unsigned* cnt = (unsigned*)d_ws;
  double* sdsl = (double*)((char*)d_ws + 256);
  double* flsl = (double*)((char*)d_ws + 256 + (size_t)N_IMFS * N_ITER * 2 * 8);
  hipLaunchKernelGGL(emd_main, dim3(NB), dim3(NT), 0, stream, x, out, cnt, sdsl, flsl);
}